// Round 4
// baseline (499.556 us; speedup 1.0000x reference)
//
#include <hip/hip_runtime.h>
#include <hip/hip_bf16.h>

#define NN 10000
#define NE 320000
#define FDIM 128
#define NRBF 20
#define PHI_DIM 384
#define NBUCK 16
#define NKEY (NN * NBUCK)

typedef unsigned int uint;
typedef unsigned short ushort;

__device__ __forceinline__ ushort f2bf(float x) {
  __hip_bfloat16 b = __float2bfloat16(x);
  return *(ushort*)&b;
}
__device__ __forceinline__ float bf2f(ushort u) {
  return __uint_as_float(((uint)u) << 16);
}
__device__ __forceinline__ int jbucket(int j) {
  return (int)(((uint)j * NBUCK) / NN);  // 0..NBUCK-1
}

// ---------------- node MLP: phi = silu(S@W1+b1)@W2 + b2 -> bf16 ----------------
__global__ void phi_kernel(const float* __restrict__ S, const float* __restrict__ W1,
                           const float* __restrict__ b1, const float* __restrict__ W2,
                           const float* __restrict__ b2, ushort* __restrict__ phi_b) {
  __shared__ float s_s[8][FDIM];
  __shared__ float h_s[8][FDIM];
  const int t = threadIdx.x;
  const int n0 = blockIdx.x * 8;
#pragma unroll
  for (int n = 0; n < 8; n++) s_s[n][t] = S[(n0 + n) * FDIM + t];
  __syncthreads();
  float acc[8];
#pragma unroll
  for (int n = 0; n < 8; n++) acc[n] = 0.f;
  for (int k = 0; k < FDIM; k++) {
    float w = W1[k * FDIM + t];
#pragma unroll
    for (int n = 0; n < 8; n++) acc[n] += s_s[n][k] * w;
  }
  float bb = b1[t];
#pragma unroll
  for (int n = 0; n < 8; n++) {
    float x = acc[n] + bb;
    h_s[n][t] = x / (1.0f + expf(-x));
  }
  __syncthreads();
  float a0[8], a1[8], a2[8];
#pragma unroll
  for (int n = 0; n < 8; n++) { a0[n] = 0.f; a1[n] = 0.f; a2[n] = 0.f; }
  for (int k = 0; k < FDIM; k++) {
    float w0 = W2[k * PHI_DIM + t];
    float w1 = W2[k * PHI_DIM + t + 128];
    float w2 = W2[k * PHI_DIM + t + 256];
#pragma unroll
    for (int n = 0; n < 8; n++) {
      float hv = h_s[n][k];
      a0[n] += hv * w0;
      a1[n] += hv * w1;
      a2[n] += hv * w2;
    }
  }
  float c0 = b2[t], c1 = b2[t + 128], c2 = b2[t + 256];
#pragma unroll
  for (int n = 0; n < 8; n++) {
    ushort* p = phi_b + (size_t)(n0 + n) * PHI_DIM;
    p[t] = f2bf(a0[n] + c0);
    p[t + 128] = f2bf(a1[n] + c1);
    p[t + 256] = f2bf(a2[n] + c2);
  }
}

// ---------------- vf -> bf16 planes [n][3][128] ----------------
__global__ void vfb_kernel(const float* __restrict__ vf, ushort* __restrict__ vfb) {
  const int n = blockIdx.x;
  const int t = threadIdx.x;
  const float* src = vf + (size_t)n * (FDIM * 3) + t * 3;
  ushort* dst = vfb + (size_t)n * (FDIM * 3);
  dst[t] = f2bf(src[0]);
  dst[t + 128] = f2bf(src[1]);
  dst[t + 256] = f2bf(src[2]);
}

// ---------------- CSR build over key = i*NBUCK + bucket(j) ----------------
__global__ void count_kernel(const int* __restrict__ idx_i, const int* __restrict__ idx_j,
                             int* __restrict__ counts) {
  int e = blockIdx.x * blockDim.x + threadIdx.x;
  if (e < NE) atomicAdd(&counts[idx_i[e] * NBUCK + jbucket(idx_j[e])], 1);
}

__global__ void scan_kernel(const int* __restrict__ counts, int* __restrict__ offsets) {
  __shared__ int s[1024];
  const int t = threadIdx.x;
  const int CH = 160;  // 1024*160 = 163840 >= NKEY
  const int base = t * CH;
  // vectorized partial sum (tail beyond NKEY reads zeroed cursor region: harmless)
  const int4* c4 = (const int4*)counts;
  int sum = 0;
#pragma unroll
  for (int q = 0; q < CH / 4; q++) {
    int4 v = c4[t * (CH / 4) + q];
    sum += v.x + v.y + v.z + v.w;
  }
  s[t] = sum;
  __syncthreads();
  for (int off = 1; off < 1024; off <<= 1) {
    int v = (t >= off) ? s[t - off] : 0;
    __syncthreads();
    s[t] += v;
    __syncthreads();
  }
  int run = s[t] - sum;  // exclusive prefix of this thread's chunk
  for (int i = 0; i < CH; i++) {
    int idx = base + i;
    if (idx < NKEY) {
      offsets[idx] = run;
      run += counts[idx];
    }
  }
  if (t == 1023) offsets[NKEY] = s[1023];
}

// stage CSR-ordered 64-B edge records: {j, cut, dx, dy, dz, pad, rbf[20] bf16}
__global__ void stage_kernel(const int* __restrict__ idx_i, const int* __restrict__ idx_j,
                             const float* __restrict__ cut, const float* __restrict__ dir,
                             const float* __restrict__ rbf, const int* __restrict__ offsets,
                             int* __restrict__ cursor, uint* __restrict__ edata) {
  int e = blockIdx.x * blockDim.x + threadIdx.x;
  if (e >= NE) return;
  int j = idx_j[e];
  int key = idx_i[e] * NBUCK + jbucket(j);
  int pos = atomicAdd(&cursor[key], 1);
  uint* d = edata + (size_t)(offsets[key] + pos) * 16;
  d[0] = (uint)j;
  d[1] = __float_as_uint(cut[e]);
  d[2] = __float_as_uint(dir[e * 3 + 0]);
  d[3] = __float_as_uint(dir[e * 3 + 1]);
  d[4] = __float_as_uint(dir[e * 3 + 2]);
  d[5] = 0u;
  const float* rb = rbf + (size_t)e * NRBF;
#pragma unroll
  for (int r = 0; r < 10; r++) {
    uint lo = (uint)f2bf(rb[2 * r]);
    uint hi = (uint)f2bf(rb[2 * r + 1]);
    d[6 + r] = (hi << 16) | lo;
  }
}

// ---------------- node-centric accumulation: 2 nodes x 128 features ----------------
// Edges of node n occupy offsets[n*NBUCK] .. offsets[(n+1)*NBUCK], j-bucket-ordered,
// so all resident blocks sweep phi_b/vfb in the same ~1 MB j-window (L2-resident).
__global__ __launch_bounds__(256, 4) void node_kernel(
    const uint* __restrict__ edata, const float* __restrict__ Wr,
    const float* __restrict__ br, const ushort* __restrict__ phi_b,
    const float* __restrict__ sf, const float* __restrict__ vf,
    const ushort* __restrict__ vfb, const int* __restrict__ offsets,
    float* __restrict__ out) {
  __shared__ float wr_s[NRBF * PHI_DIM];  // 30720 B
  const int t = threadIdx.x;
  const int f = t & 127;
  const int g = t >> 7;  // node slot 0..1
  for (int i = t; i < NRBF * PHI_DIM; i += 256) wr_s[i] = Wr[i];
  __syncthreads();
  const int n = blockIdx.x * 2 + g;
  const int beg = offsets[n * NBUCK], end = offsets[(n + 1) * NBUCK];
  const float br0 = br[f], br1 = br[f + 128], br2 = br[f + 256];
  float ss = 0.f, vx = 0.f, vy = 0.f, vz = 0.f;
  for (int p = beg; p < end; p++) {
    const int pu = __builtin_amdgcn_readfirstlane(p);
    const uint4* rec = (const uint4*)(edata + (size_t)pu * 16);
    uint4 q0 = rec[0];
    uint4 q1 = rec[1];
    uint4 q2 = rec[2];
    uint4 q3 = rec[3];
    const int j = (int)q0.x;
    const float c = __uint_as_float(q0.y);
    const float dx = __uint_as_float(q0.z);
    const float dy = __uint_as_float(q0.w);
    const float dz = __uint_as_float(q1.x);
    uint rbp[10] = {q1.z, q1.w, q2.x, q2.y, q2.z, q2.w, q3.x, q3.y, q3.z, q3.w};
    float rv[NRBF];
#pragma unroll
    for (int r = 0; r < 10; r++) {
      rv[2 * r] = __uint_as_float(rbp[r] << 16);
      rv[2 * r + 1] = __uint_as_float(rbp[r] & 0xffff0000u);
    }
    float g0 = br0, g1 = br1, g2 = br2;
#pragma unroll
    for (int r = 0; r < NRBF; r++) {
      float rvv = rv[r];
      g0 += rvv * wr_s[r * PHI_DIM + f];
      g1 += rvv * wr_s[r * PHI_DIM + f + 128];
      g2 += rvv * wr_s[r * PHI_DIM + f + 256];
    }
    g0 *= c; g1 *= c; g2 *= c;
    const ushort* pj = phi_b + (size_t)j * PHI_DIM;
    const float vv = bf2f(pj[f]) * g0;
    const float sv = bf2f(pj[f + 128]) * g1;
    const float vs = bf2f(pj[f + 256]) * g2;
    ss += sv;
    const ushort* vj = vfb + (size_t)j * PHI_DIM;
    vx += bf2f(vj[f]) * vv + vs * dx;
    vy += bf2f(vj[f + 128]) * vv + vs * dy;
    vz += bf2f(vj[f + 256]) * vv + vs * dz;
  }
  const float inv = 1.0f / (float)(end - beg);
  out[(size_t)n * FDIM + f] = sf[(size_t)n * FDIM + f] + ss * inv;
  float* ov = out + (size_t)NN * FDIM + (size_t)n * (FDIM * 3) + f * 3;
  const float* iv = vf + (size_t)n * (FDIM * 3) + f * 3;
  ov[0] = iv[0] + vx * inv;
  ov[1] = iv[1] + vy * inv;
  ov[2] = iv[2] + vz * inv;
}

extern "C" void kernel_launch(void* const* d_in, const int* in_sizes, int n_in,
                              void* d_out, int out_size, void* d_ws, size_t ws_size,
                              hipStream_t stream) {
  const int* idx_i = (const int*)d_in[0];
  const int* idx_j = (const int*)d_in[1];
  const float* rel_dir = (const float*)d_in[2];
  const float* cut = (const float*)d_in[3];
  const float* rbf = (const float*)d_in[4];
  const float* sf = (const float*)d_in[5];
  const float* vf = (const float*)d_in[6];
  const float* W1 = (const float*)d_in[7];
  const float* b1 = (const float*)d_in[8];
  const float* W2 = (const float*)d_in[9];
  const float* b2 = (const float*)d_in[10];
  const float* Wr = (const float*)d_in[11];
  const float* br = (const float*)d_in[12];
  float* out = (float*)d_out;

  // workspace layout (bytes):
  //   counts : [0, 640064)               160016 ints
  //   cursor : [640064, 1280128)         160016 ints
  //   offsets: [1280128, 1920196)        160017 ints -> next region at 1920256
  //   edata  : [1920256, 22400256)       320000 * 64 B
  //   phi_b  : [22400256, 30080256)      10000*384 ushort
  //   vfb    : [30080256, 37760256)      10000*384 ushort
  char* w = (char*)d_ws;
  int* counts = (int*)w;
  int* cursor = (int*)(w + 640064);
  int* offsets = (int*)(w + 1280128);
  uint* edata = (uint*)(w + 1920256);
  ushort* phi_b = (ushort*)(w + 22400256);
  ushort* vfb = (ushort*)(w + 30080256);

  hipMemsetAsync(w, 0, 1280128, stream);  // zero counts + cursor
  hipLaunchKernelGGL(phi_kernel, dim3(NN / 8), dim3(128), 0, stream, sf, W1, b1, W2, b2, phi_b);
  hipLaunchKernelGGL(vfb_kernel, dim3(NN), dim3(128), 0, stream, vf, vfb);
  hipLaunchKernelGGL(count_kernel, dim3((NE + 255) / 256), dim3(256), 0, stream, idx_i, idx_j,
                     counts);
  hipLaunchKernelGGL(scan_kernel, dim3(1), dim3(1024), 0, stream, counts, offsets);
  hipLaunchKernelGGL(stage_kernel, dim3((NE + 255) / 256), dim3(256), 0, stream, idx_i, idx_j,
                     cut, rel_dir, rbf, offsets, cursor, edata);
  hipLaunchKernelGGL(node_kernel, dim3(NN / 2), dim3(256), 0, stream, edata, Wr, br, phi_b, sf,
                     vf, vfb, offsets, out);
}

// Round 5
// 278.083 us; speedup vs baseline: 1.7964x; 1.7964x over previous
//
#include <hip/hip_runtime.h>
#include <hip/hip_bf16.h>

#define NN 10000
#define NE 320000
#define FDIM 128
#define NRBF 20
#define PHI_DIM 384
#define NBUCK 16
#define NKEY (NN * NBUCK)
#define SCAN_BLOCKS 625  // NKEY / 256

typedef unsigned int uint;
typedef unsigned short ushort;

__device__ __forceinline__ ushort f2bf(float x) {
  __hip_bfloat16 b = __float2bfloat16(x);
  return *(ushort*)&b;
}
__device__ __forceinline__ float bf2f(ushort u) {
  return __uint_as_float(((uint)u) << 16);
}
__device__ __forceinline__ int jbucket(int j) {
  return (int)(((uint)j * NBUCK) / NN);  // 0..NBUCK-1
}

// ---------------- node MLP: phi = silu(S@W1+b1)@W2 + b2 -> bf16 ----------------
__global__ void phi_kernel(const float* __restrict__ S, const float* __restrict__ W1,
                           const float* __restrict__ b1, const float* __restrict__ W2,
                           const float* __restrict__ b2, ushort* __restrict__ phi_b) {
  __shared__ float s_s[8][FDIM];
  __shared__ float h_s[8][FDIM];
  const int t = threadIdx.x;
  const int n0 = blockIdx.x * 8;
#pragma unroll
  for (int n = 0; n < 8; n++) s_s[n][t] = S[(n0 + n) * FDIM + t];
  __syncthreads();
  float acc[8];
#pragma unroll
  for (int n = 0; n < 8; n++) acc[n] = 0.f;
  for (int k = 0; k < FDIM; k++) {
    float w = W1[k * FDIM + t];
#pragma unroll
    for (int n = 0; n < 8; n++) acc[n] += s_s[n][k] * w;
  }
  float bb = b1[t];
#pragma unroll
  for (int n = 0; n < 8; n++) {
    float x = acc[n] + bb;
    h_s[n][t] = x / (1.0f + expf(-x));
  }
  __syncthreads();
  float a0[8], a1[8], a2[8];
#pragma unroll
  for (int n = 0; n < 8; n++) { a0[n] = 0.f; a1[n] = 0.f; a2[n] = 0.f; }
  for (int k = 0; k < FDIM; k++) {
    float w0 = W2[k * PHI_DIM + t];
    float w1 = W2[k * PHI_DIM + t + 128];
    float w2 = W2[k * PHI_DIM + t + 256];
#pragma unroll
    for (int n = 0; n < 8; n++) {
      float hv = h_s[n][k];
      a0[n] += hv * w0;
      a1[n] += hv * w1;
      a2[n] += hv * w2;
    }
  }
  float c0 = b2[t], c1 = b2[t + 128], c2 = b2[t + 256];
#pragma unroll
  for (int n = 0; n < 8; n++) {
    ushort* p = phi_b + (size_t)(n0 + n) * PHI_DIM;
    p[t] = f2bf(a0[n] + c0);
    p[t + 128] = f2bf(a1[n] + c1);
    p[t + 256] = f2bf(a2[n] + c2);
  }
}

// ---------------- vf -> bf16 planes [n][3][128] ----------------
__global__ void vfb_kernel(const float* __restrict__ vf, ushort* __restrict__ vfb) {
  const int n = blockIdx.x;
  const int t = threadIdx.x;
  const float* src = vf + (size_t)n * (FDIM * 3) + t * 3;
  ushort* dst = vfb + (size_t)n * (FDIM * 3);
  dst[t] = f2bf(src[0]);
  dst[t + 128] = f2bf(src[1]);
  dst[t + 256] = f2bf(src[2]);
}

// ---------------- CSR build over key = i*NBUCK + bucket(j) ----------------
__global__ void count_kernel(const int* __restrict__ idx_i, const int* __restrict__ idx_j,
                             int* __restrict__ counts) {
  int e = blockIdx.x * blockDim.x + threadIdx.x;
  if (e < NE) atomicAdd(&counts[idx_i[e] * NBUCK + jbucket(idx_j[e])], 1);
}

// ---------------- hierarchical scan: block scan -> sum scan -> add base ----------------
__global__ void scan1_kernel(const int* __restrict__ counts, int* __restrict__ offsets,
                             int* __restrict__ blocksums) {
  __shared__ int s[256];
  const int t = threadIdx.x;
  const int idx = blockIdx.x * 256 + t;
  const int c = counts[idx];
  s[t] = c;
  __syncthreads();
  for (int off = 1; off < 256; off <<= 1) {
    int v = (t >= off) ? s[t - off] : 0;
    __syncthreads();
    s[t] += v;
    __syncthreads();
  }
  offsets[idx] = s[t] - c;  // exclusive within block
  if (t == 255) blocksums[blockIdx.x] = s[255];
}

__global__ void scan2_kernel(int* __restrict__ blocksums, int* __restrict__ offsets) {
  __shared__ int s[1024];
  const int t = threadIdx.x;
  int v0 = (t < SCAN_BLOCKS) ? blocksums[t] : 0;
  s[t] = v0;
  __syncthreads();
  for (int off = 1; off < 1024; off <<= 1) {
    int v = (t >= off) ? s[t - off] : 0;
    __syncthreads();
    s[t] += v;
    __syncthreads();
  }
  if (t < SCAN_BLOCKS) blocksums[t] = s[t] - v0;  // exclusive base per block
  if (t == SCAN_BLOCKS - 1) offsets[NKEY] = s[t];  // total = NE
}

__global__ void scan3_kernel(int* __restrict__ offsets, const int* __restrict__ blocksums) {
  const int idx = blockIdx.x * 256 + threadIdx.x;
  offsets[idx] += blocksums[blockIdx.x];
}

// stage CSR-ordered 64-B edge records: {j, cut, dx, dy, dz, pad, rbf[20] bf16}
__global__ void stage_kernel(const int* __restrict__ idx_i, const int* __restrict__ idx_j,
                             const float* __restrict__ cut, const float* __restrict__ dir,
                             const float* __restrict__ rbf, const int* __restrict__ offsets,
                             int* __restrict__ cursor, uint* __restrict__ edata) {
  int e = blockIdx.x * blockDim.x + threadIdx.x;
  if (e >= NE) return;
  int j = idx_j[e];
  int key = idx_i[e] * NBUCK + jbucket(j);
  int pos = atomicAdd(&cursor[key], 1);
  uint* d = edata + (size_t)(offsets[key] + pos) * 16;
  d[0] = (uint)j;
  d[1] = __float_as_uint(cut[e]);
  d[2] = __float_as_uint(dir[e * 3 + 0]);
  d[3] = __float_as_uint(dir[e * 3 + 1]);
  d[4] = __float_as_uint(dir[e * 3 + 2]);
  d[5] = 0u;
  const float* rb = rbf + (size_t)e * NRBF;
#pragma unroll
  for (int r = 0; r < 10; r++) {
    uint lo = (uint)f2bf(rb[2 * r]);
    uint hi = (uint)f2bf(rb[2 * r + 1]);
    d[6 + r] = (hi << 16) | lo;
  }
}

// ---------------- node-centric accumulation: 2 nodes x 128 features ----------------
__global__ __launch_bounds__(256, 4) void node_kernel(
    const uint* __restrict__ edata, const float* __restrict__ Wr,
    const float* __restrict__ br, const ushort* __restrict__ phi_b,
    const float* __restrict__ sf, const float* __restrict__ vf,
    const ushort* __restrict__ vfb, const int* __restrict__ offsets,
    float* __restrict__ out) {
  __shared__ float wr_s[NRBF * PHI_DIM];  // 30720 B
  const int t = threadIdx.x;
  const int f = t & 127;
  const int g = t >> 7;  // node slot 0..1
  for (int i = t; i < NRBF * PHI_DIM; i += 256) wr_s[i] = Wr[i];
  __syncthreads();
  const int n = blockIdx.x * 2 + g;
  const int beg = offsets[n * NBUCK], end = offsets[(n + 1) * NBUCK];
  const float br0 = br[f], br1 = br[f + 128], br2 = br[f + 256];
  float ss = 0.f, vx = 0.f, vy = 0.f, vz = 0.f;
  for (int p = beg; p < end; p++) {
    const int pu = __builtin_amdgcn_readfirstlane(p);
    const uint4* rec = (const uint4*)(edata + (size_t)pu * 16);
    uint4 q0 = rec[0];
    uint4 q1 = rec[1];
    uint4 q2 = rec[2];
    uint4 q3 = rec[3];
    const int j = (int)q0.x;
    const float c = __uint_as_float(q0.y);
    const float dx = __uint_as_float(q0.z);
    const float dy = __uint_as_float(q0.w);
    const float dz = __uint_as_float(q1.x);
    uint rbp[10] = {q1.z, q1.w, q2.x, q2.y, q2.z, q2.w, q3.x, q3.y, q3.z, q3.w};
    float rv[NRBF];
#pragma unroll
    for (int r = 0; r < 10; r++) {
      rv[2 * r] = __uint_as_float(rbp[r] << 16);
      rv[2 * r + 1] = __uint_as_float(rbp[r] & 0xffff0000u);
    }
    float g0 = br0, g1 = br1, g2 = br2;
#pragma unroll
    for (int r = 0; r < NRBF; r++) {
      float rvv = rv[r];
      g0 += rvv * wr_s[r * PHI_DIM + f];
      g1 += rvv * wr_s[r * PHI_DIM + f + 128];
      g2 += rvv * wr_s[r * PHI_DIM + f + 256];
    }
    g0 *= c; g1 *= c; g2 *= c;
    const ushort* pj = phi_b + (size_t)j * PHI_DIM;
    const float vv = bf2f(pj[f]) * g0;
    const float sv = bf2f(pj[f + 128]) * g1;
    const float vs = bf2f(pj[f + 256]) * g2;
    ss += sv;
    const ushort* vj = vfb + (size_t)j * PHI_DIM;
    vx += bf2f(vj[f]) * vv + vs * dx;
    vy += bf2f(vj[f + 128]) * vv + vs * dy;
    vz += bf2f(vj[f + 256]) * vv + vs * dz;
  }
  const float inv = 1.0f / (float)(end - beg);
  out[(size_t)n * FDIM + f] = sf[(size_t)n * FDIM + f] + ss * inv;
  float* ov = out + (size_t)NN * FDIM + (size_t)n * (FDIM * 3) + f * 3;
  const float* iv = vf + (size_t)n * (FDIM * 3) + f * 3;
  ov[0] = iv[0] + vx * inv;
  ov[1] = iv[1] + vy * inv;
  ov[2] = iv[2] + vz * inv;
}

extern "C" void kernel_launch(void* const* d_in, const int* in_sizes, int n_in,
                              void* d_out, int out_size, void* d_ws, size_t ws_size,
                              hipStream_t stream) {
  const int* idx_i = (const int*)d_in[0];
  const int* idx_j = (const int*)d_in[1];
  const float* rel_dir = (const float*)d_in[2];
  const float* cut = (const float*)d_in[3];
  const float* rbf = (const float*)d_in[4];
  const float* sf = (const float*)d_in[5];
  const float* vf = (const float*)d_in[6];
  const float* W1 = (const float*)d_in[7];
  const float* b1 = (const float*)d_in[8];
  const float* W2 = (const float*)d_in[9];
  const float* b2 = (const float*)d_in[10];
  const float* Wr = (const float*)d_in[11];
  const float* br = (const float*)d_in[12];
  float* out = (float*)d_out;

  // workspace layout (bytes):
  //   counts   : [0, 640000)             NKEY ints
  //   cursor   : [640000, 1280000)       NKEY ints
  //   offsets  : [1280000, 1920064)      NKEY+1 ints (padded)
  //   blocksums: [1920064, 1922624)      625 ints (padded to 2560)
  //   edata    : [1922624, 22402624)     320000 * 64 B
  //   phi_b    : [22402624, 30082624)    10000*384 ushort
  //   vfb      : [30082624, 37762624)    10000*384 ushort
  char* w = (char*)d_ws;
  int* counts = (int*)w;
  int* cursor = (int*)(w + 640000);
  int* offsets = (int*)(w + 1280000);
  int* blocksums = (int*)(w + 1920064);
  uint* edata = (uint*)(w + 1922624);
  ushort* phi_b = (ushort*)(w + 22402624);
  ushort* vfb = (ushort*)(w + 30082624);

  hipMemsetAsync(w, 0, 1280000, stream);  // zero counts + cursor
  hipLaunchKernelGGL(phi_kernel, dim3(NN / 8), dim3(128), 0, stream, sf, W1, b1, W2, b2, phi_b);
  hipLaunchKernelGGL(vfb_kernel, dim3(NN), dim3(128), 0, stream, vf, vfb);
  hipLaunchKernelGGL(count_kernel, dim3((NE + 255) / 256), dim3(256), 0, stream, idx_i, idx_j,
                     counts);
  hipLaunchKernelGGL(scan1_kernel, dim3(SCAN_BLOCKS), dim3(256), 0, stream, counts, offsets,
                     blocksums);
  hipLaunchKernelGGL(scan2_kernel, dim3(1), dim3(1024), 0, stream, blocksums, offsets);
  hipLaunchKernelGGL(scan3_kernel, dim3(SCAN_BLOCKS), dim3(256), 0, stream, offsets, blocksums);
  hipLaunchKernelGGL(stage_kernel, dim3((NE + 255) / 256), dim3(256), 0, stream, idx_i, idx_j,
                     cut, rel_dir, rbf, offsets, cursor, edata);
  hipLaunchKernelGGL(node_kernel, dim3(NN / 2), dim3(256), 0, stream, edata, Wr, br, phi_b, sf,
                     vf, vfb, offsets, out);
}

// Round 7
// 232.437 us; speedup vs baseline: 2.1492x; 1.1964x over previous
//
#include <hip/hip_runtime.h>
#include <hip/hip_bf16.h>

#define NN 10000
#define NE 320000
#define FDIM 128
#define NRBF 20
#define PHI_DIM 384
#define NKEY NN
#define SCAN_BLOCKS 40  // 40*256 = 10240 >= NKEY+1

typedef unsigned int uint;
typedef unsigned short ushort;

__device__ __forceinline__ ushort f2bf(float x) {
  __hip_bfloat16 b = __float2bfloat16(x);
  return *(ushort*)&b;
}
__device__ __forceinline__ float bf2f(ushort u) {
  return __uint_as_float(((uint)u) << 16);
}

// ---------------- node MLP: phi = silu(S@W1+b1)@W2 + b2 -> bf16 ----------------
__global__ void phi_kernel(const float* __restrict__ S, const float* __restrict__ W1,
                           const float* __restrict__ b1, const float* __restrict__ W2,
                           const float* __restrict__ b2, ushort* __restrict__ phi_b) {
  __shared__ float s_s[8][FDIM];
  __shared__ float h_s[8][FDIM];
  const int t = threadIdx.x;
  const int n0 = blockIdx.x * 8;
#pragma unroll
  for (int n = 0; n < 8; n++) s_s[n][t] = S[(n0 + n) * FDIM + t];
  __syncthreads();
  float acc[8];
#pragma unroll
  for (int n = 0; n < 8; n++) acc[n] = 0.f;
  for (int k = 0; k < FDIM; k++) {
    float w = W1[k * FDIM + t];
#pragma unroll
    for (int n = 0; n < 8; n++) acc[n] += s_s[n][k] * w;
  }
  float bb = b1[t];
#pragma unroll
  for (int n = 0; n < 8; n++) {
    float x = acc[n] + bb;
    h_s[n][t] = x / (1.0f + expf(-x));
  }
  __syncthreads();
  float a0[8], a1[8], a2[8];
#pragma unroll
  for (int n = 0; n < 8; n++) { a0[n] = 0.f; a1[n] = 0.f; a2[n] = 0.f; }
  for (int k = 0; k < FDIM; k++) {
    float w0 = W2[k * PHI_DIM + t];
    float w1 = W2[k * PHI_DIM + t + 128];
    float w2 = W2[k * PHI_DIM + t + 256];
#pragma unroll
    for (int n = 0; n < 8; n++) {
      float hv = h_s[n][k];
      a0[n] += hv * w0;
      a1[n] += hv * w1;
      a2[n] += hv * w2;
    }
  }
  float c0 = b2[t], c1 = b2[t + 128], c2 = b2[t + 256];
#pragma unroll
  for (int n = 0; n < 8; n++) {
    ushort* p = phi_b + (size_t)(n0 + n) * PHI_DIM;
    p[t] = f2bf(a0[n] + c0);
    p[t + 128] = f2bf(a1[n] + c1);
    p[t + 256] = f2bf(a2[n] + c2);
  }
}

// ---------------- vf -> bf16 planes [n][3][128] ----------------
__global__ void vfb_kernel(const float* __restrict__ vf, ushort* __restrict__ vfb) {
  const int n = blockIdx.x;
  const int t = threadIdx.x;
  const float* src = vf + (size_t)n * (FDIM * 3) + t * 3;
  ushort* dst = vfb + (size_t)n * (FDIM * 3);
  dst[t] = f2bf(src[0]);
  dst[t + 128] = f2bf(src[1]);
  dst[t + 256] = f2bf(src[2]);
}

// ---------------- CSR build over i ----------------
__global__ void count_kernel(const int* __restrict__ idx_i, int* __restrict__ counts) {
  int e = blockIdx.x * blockDim.x + threadIdx.x;
  if (e < NE) atomicAdd(&counts[idx_i[e]], 1);
}

// ---------------- hierarchical scan: block scan -> sum scan -> add base ----------------
__global__ void scan1_kernel(const int* __restrict__ counts, int* __restrict__ offsets,
                             int* __restrict__ blocksums) {
  __shared__ int s[256];
  const int t = threadIdx.x;
  const int idx = blockIdx.x * 256 + t;
  const int c = counts[idx];  // region zero-padded to 10240
  s[t] = c;
  __syncthreads();
  for (int off = 1; off < 256; off <<= 1) {
    int v = (t >= off) ? s[t - off] : 0;
    __syncthreads();
    s[t] += v;
    __syncthreads();
  }
  if (idx < NKEY) offsets[idx] = s[t] - c;  // exclusive within block
  if (t == 255) blocksums[blockIdx.x] = s[255];
}

__global__ void scan2_kernel(int* __restrict__ blocksums, int* __restrict__ offsets) {
  __shared__ int s[64];
  const int t = threadIdx.x;  // 64 threads
  int v0 = (t < SCAN_BLOCKS) ? blocksums[t] : 0;
  s[t] = v0;
  __syncthreads();
  for (int off = 1; off < 64; off <<= 1) {
    int v = (t >= off) ? s[t - off] : 0;
    __syncthreads();
    s[t] += v;
    __syncthreads();
  }
  if (t < SCAN_BLOCKS) blocksums[t] = s[t] - v0;   // exclusive base per block
  if (t == SCAN_BLOCKS - 1) offsets[NKEY] = s[t];  // total = NE
}

__global__ void scan3_kernel(int* __restrict__ offsets, const int* __restrict__ blocksums) {
  const int idx = blockIdx.x * 256 + threadIdx.x;
  if (idx < NKEY) offsets[idx] += blocksums[blockIdx.x];  // NB: must NOT touch offsets[NKEY]
}

// stage CSR-ordered 64-B edge records: {j, cut, dx, dy, dz, pad, rbf[20] bf16}
__global__ void stage_kernel(const int* __restrict__ idx_i, const int* __restrict__ idx_j,
                             const float* __restrict__ cut, const float* __restrict__ dir,
                             const float* __restrict__ rbf, const int* __restrict__ offsets,
                             int* __restrict__ cursor, uint* __restrict__ edata) {
  int e = blockIdx.x * blockDim.x + threadIdx.x;
  if (e >= NE) return;
  int i = idx_i[e];
  int pos = atomicAdd(&cursor[i], 1);
  uint* d = edata + (size_t)(offsets[i] + pos) * 16;
  d[0] = (uint)idx_j[e];
  d[1] = __float_as_uint(cut[e]);
  d[2] = __float_as_uint(dir[e * 3 + 0]);
  d[3] = __float_as_uint(dir[e * 3 + 1]);
  d[4] = __float_as_uint(dir[e * 3 + 2]);
  d[5] = 0u;
  const float* rb = rbf + (size_t)e * NRBF;
#pragma unroll
  for (int r = 0; r < 10; r++) {
    uint lo = (uint)f2bf(rb[2 * r]);
    uint hi = (uint)f2bf(rb[2 * r + 1]);
    d[6 + r] = (hi << 16) | lo;
  }
}

// ---------------- node-centric accumulation: 2 nodes x 128 features ----------------
// Wr columns for this thread's 3 features live in 60 registers -> zero LDS in loop.
__global__ __launch_bounds__(256, 4) void node_kernel(
    const uint* __restrict__ edata, const float* __restrict__ Wr,
    const float* __restrict__ br, const ushort* __restrict__ phi_b,
    const float* __restrict__ sf, const float* __restrict__ vf,
    const ushort* __restrict__ vfb, const int* __restrict__ offsets,
    float* __restrict__ out) {
  const int t = threadIdx.x;
  const int f = t & 127;
  const int g = t >> 7;  // node slot 0..1
  float wrA[NRBF], wrB[NRBF], wrC[NRBF];
#pragma unroll
  for (int r = 0; r < NRBF; r++) {
    wrA[r] = Wr[r * PHI_DIM + f];
    wrB[r] = Wr[r * PHI_DIM + f + 128];
    wrC[r] = Wr[r * PHI_DIM + f + 256];
  }
  const int n = blockIdx.x * 2 + g;
  const int beg = offsets[n], end = offsets[n + 1];
  const float br0 = br[f], br1 = br[f + 128], br2 = br[f + 256];
  float ss = 0.f, vx = 0.f, vy = 0.f, vz = 0.f;
  for (int p = beg; p < end; p++) {
    const int pu = __builtin_amdgcn_readfirstlane(p);
    const uint4* rec = (const uint4*)(edata + (size_t)pu * 16);
    uint4 q0 = rec[0];
    uint4 q1 = rec[1];
    uint4 q2 = rec[2];
    uint4 q3 = rec[3];
    const int j = (int)q0.x;
    const float c = __uint_as_float(q0.y);
    const float dx = __uint_as_float(q0.z);
    const float dy = __uint_as_float(q0.w);
    const float dz = __uint_as_float(q1.x);
    uint rbp[10] = {q1.z, q1.w, q2.x, q2.y, q2.z, q2.w, q3.x, q3.y, q3.z, q3.w};
    float rv[NRBF];
#pragma unroll
    for (int r = 0; r < 10; r++) {
      rv[2 * r] = __uint_as_float(rbp[r] << 16);
      rv[2 * r + 1] = __uint_as_float(rbp[r] & 0xffff0000u);
    }
    float g0 = br0, g1 = br1, g2 = br2;
#pragma unroll
    for (int r = 0; r < NRBF; r++) {
      float rvv = rv[r];
      g0 += rvv * wrA[r];
      g1 += rvv * wrB[r];
      g2 += rvv * wrC[r];
    }
    g0 *= c; g1 *= c; g2 *= c;
    const ushort* pj = phi_b + (size_t)j * PHI_DIM;
    const float vv = bf2f(pj[f]) * g0;
    const float sv = bf2f(pj[f + 128]) * g1;
    const float vs = bf2f(pj[f + 256]) * g2;
    ss += sv;
    const ushort* vj = vfb + (size_t)j * PHI_DIM;
    vx += bf2f(vj[f]) * vv + vs * dx;
    vy += bf2f(vj[f + 128]) * vv + vs * dy;
    vz += bf2f(vj[f + 256]) * vv + vs * dz;
  }
  const float inv = 1.0f / (float)(end - beg);
  out[(size_t)n * FDIM + f] = sf[(size_t)n * FDIM + f] + ss * inv;
  float* ov = out + (size_t)NN * FDIM + (size_t)n * (FDIM * 3) + f * 3;
  const float* iv = vf + (size_t)n * (FDIM * 3) + f * 3;
  ov[0] = iv[0] + vx * inv;
  ov[1] = iv[1] + vy * inv;
  ov[2] = iv[2] + vz * inv;
}

extern "C" void kernel_launch(void* const* d_in, const int* in_sizes, int n_in,
                              void* d_out, int out_size, void* d_ws, size_t ws_size,
                              hipStream_t stream) {
  const int* idx_i = (const int*)d_in[0];
  const int* idx_j = (const int*)d_in[1];
  const float* rel_dir = (const float*)d_in[2];
  const float* cut = (const float*)d_in[3];
  const float* rbf = (const float*)d_in[4];
  const float* sf = (const float*)d_in[5];
  const float* vf = (const float*)d_in[6];
  const float* W1 = (const float*)d_in[7];
  const float* b1 = (const float*)d_in[8];
  const float* W2 = (const float*)d_in[9];
  const float* b2 = (const float*)d_in[10];
  const float* Wr = (const float*)d_in[11];
  const float* br = (const float*)d_in[12];
  float* out = (float*)d_out;

  // workspace layout (bytes):
  //   counts   : [0, 40960)          10240 ints (zero-padded)
  //   cursor   : [40960, 81920)      10240 ints (zero-padded)
  //   offsets  : [81920, 122944)     10241 ints (padded)
  //   blocksums: [122944, 123200)    40 ints (padded to 64)
  //   edata    : [123200, 20603200)  320000 * 64 B
  //   phi_b    : [20603200, 28283200)
  //   vfb      : [28283200, 35963200)
  char* w = (char*)d_ws;
  int* counts = (int*)w;
  int* cursor = (int*)(w + 40960);
  int* offsets = (int*)(w + 81920);
  int* blocksums = (int*)(w + 122944);
  uint* edata = (uint*)(w + 123200);
  ushort* phi_b = (ushort*)(w + 20603200);
  ushort* vfb = (ushort*)(w + 28283200);

  hipMemsetAsync(w, 0, 81920, stream);  // zero counts + cursor
  hipLaunchKernelGGL(phi_kernel, dim3(NN / 8), dim3(128), 0, stream, sf, W1, b1, W2, b2, phi_b);
  hipLaunchKernelGGL(vfb_kernel, dim3(NN), dim3(128), 0, stream, vf, vfb);
  hipLaunchKernelGGL(count_kernel, dim3((NE + 255) / 256), dim3(256), 0, stream, idx_i, counts);
  hipLaunchKernelGGL(scan1_kernel, dim3(SCAN_BLOCKS), dim3(256), 0, stream, counts, offsets,
                     blocksums);
  hipLaunchKernelGGL(scan2_kernel, dim3(1), dim3(64), 0, stream, blocksums, offsets);
  hipLaunchKernelGGL(scan3_kernel, dim3(SCAN_BLOCKS), dim3(256), 0, stream, offsets, blocksums);
  hipLaunchKernelGGL(stage_kernel, dim3((NE + 255) / 256), dim3(256), 0, stream, idx_i, idx_j,
                     cut, rel_dir, rbf, offsets, cursor, edata);
  hipLaunchKernelGGL(node_kernel, dim3(NN / 2), dim3(256), 0, stream, edata, Wr, br, phi_b, sf,
                     vf, vfb, offsets, out);
}

// Round 8
// 204.918 us; speedup vs baseline: 2.4378x; 1.1343x over previous
//
#include <hip/hip_runtime.h>
#include <hip/hip_bf16.h>

#define NN 10000
#define NE 320000
#define FDIM 128
#define NRBF 20
#define PHI_DIM 384
#define NKEY NN
#define SCAN_BLOCKS 40  // 40*256 = 10240 >= NKEY+1

typedef unsigned int uint;
typedef unsigned short ushort;

#if __has_builtin(__builtin_amdgcn_fdot2_f32_bf16)
#define USE_DOT2 1
typedef __bf16 bf16x2 __attribute__((ext_vector_type(2)));
#else
#define USE_DOT2 0
#endif

__device__ __forceinline__ ushort f2bf(float x) {
  __hip_bfloat16 b = __float2bfloat16(x);
  return *(ushort*)&b;
}
__device__ __forceinline__ float bf2f(ushort u) {
  return __uint_as_float(((uint)u) << 16);
}

// ---------------- node MLP: phi = silu(S@W1+b1)@W2 + b2 -> bf16 ----------------
__global__ void phi_kernel(const float* __restrict__ S, const float* __restrict__ W1,
                           const float* __restrict__ b1, const float* __restrict__ W2,
                           const float* __restrict__ b2, ushort* __restrict__ phi_b) {
  __shared__ float s_s[8][FDIM];
  __shared__ float h_s[8][FDIM];
  const int t = threadIdx.x;
  const int n0 = blockIdx.x * 8;
#pragma unroll
  for (int n = 0; n < 8; n++) s_s[n][t] = S[(n0 + n) * FDIM + t];
  __syncthreads();
  float acc[8];
#pragma unroll
  for (int n = 0; n < 8; n++) acc[n] = 0.f;
  for (int k = 0; k < FDIM; k++) {
    float w = W1[k * FDIM + t];
#pragma unroll
    for (int n = 0; n < 8; n++) acc[n] += s_s[n][k] * w;
  }
  float bb = b1[t];
#pragma unroll
  for (int n = 0; n < 8; n++) {
    float x = acc[n] + bb;
    h_s[n][t] = x / (1.0f + expf(-x));
  }
  __syncthreads();
  float a0[8], a1[8], a2[8];
#pragma unroll
  for (int n = 0; n < 8; n++) { a0[n] = 0.f; a1[n] = 0.f; a2[n] = 0.f; }
  for (int k = 0; k < FDIM; k++) {
    float w0 = W2[k * PHI_DIM + t];
    float w1 = W2[k * PHI_DIM + t + 128];
    float w2 = W2[k * PHI_DIM + t + 256];
#pragma unroll
    for (int n = 0; n < 8; n++) {
      float hv = h_s[n][k];
      a0[n] += hv * w0;
      a1[n] += hv * w1;
      a2[n] += hv * w2;
    }
  }
  float c0 = b2[t], c1 = b2[t + 128], c2 = b2[t + 256];
#pragma unroll
  for (int n = 0; n < 8; n++) {
    ushort* p = phi_b + (size_t)(n0 + n) * PHI_DIM;
    p[t] = f2bf(a0[n] + c0);
    p[t + 128] = f2bf(a1[n] + c1);
    p[t + 256] = f2bf(a2[n] + c2);
  }
}

// ---------------- vf -> bf16 planes [n][3][128] ----------------
__global__ void vfb_kernel(const float* __restrict__ vf, ushort* __restrict__ vfb) {
  const int n = blockIdx.x;
  const int t = threadIdx.x;
  const float* src = vf + (size_t)n * (FDIM * 3) + t * 3;
  ushort* dst = vfb + (size_t)n * (FDIM * 3);
  dst[t] = f2bf(src[0]);
  dst[t + 128] = f2bf(src[1]);
  dst[t + 256] = f2bf(src[2]);
}

// ---------------- CSR build over i ----------------
__global__ void count_kernel(const int* __restrict__ idx_i, int* __restrict__ counts) {
  int e = blockIdx.x * blockDim.x + threadIdx.x;
  if (e < NE) atomicAdd(&counts[idx_i[e]], 1);
}

// ---------------- hierarchical scan: block scan -> sum scan -> add base ----------------
__global__ void scan1_kernel(const int* __restrict__ counts, int* __restrict__ offsets,
                             int* __restrict__ blocksums) {
  __shared__ int s[256];
  const int t = threadIdx.x;
  const int idx = blockIdx.x * 256 + t;
  const int c = counts[idx];  // region zero-padded to 10240
  s[t] = c;
  __syncthreads();
  for (int off = 1; off < 256; off <<= 1) {
    int v = (t >= off) ? s[t - off] : 0;
    __syncthreads();
    s[t] += v;
    __syncthreads();
  }
  if (idx < NKEY) offsets[idx] = s[t] - c;  // exclusive within block
  if (t == 255) blocksums[blockIdx.x] = s[255];
}

__global__ void scan2_kernel(int* __restrict__ blocksums, int* __restrict__ offsets) {
  __shared__ int s[64];
  const int t = threadIdx.x;  // 64 threads
  int v0 = (t < SCAN_BLOCKS) ? blocksums[t] : 0;
  s[t] = v0;
  __syncthreads();
  for (int off = 1; off < 64; off <<= 1) {
    int v = (t >= off) ? s[t - off] : 0;
    __syncthreads();
    s[t] += v;
    __syncthreads();
  }
  if (t < SCAN_BLOCKS) blocksums[t] = s[t] - v0;   // exclusive base per block
  if (t == SCAN_BLOCKS - 1) offsets[NKEY] = s[t];  // total = NE
}

__global__ void scan3_kernel(int* __restrict__ offsets, const int* __restrict__ blocksums) {
  const int idx = blockIdx.x * 256 + threadIdx.x;
  if (idx < NKEY) offsets[idx] += blocksums[blockIdx.x];  // must NOT touch offsets[NKEY]
}

// stage CSR-ordered 64-B edge records: {j, cut, dx, dy, dz, pad, rbf[20] bf16}
__global__ void stage_kernel(const int* __restrict__ idx_i, const int* __restrict__ idx_j,
                             const float* __restrict__ cut, const float* __restrict__ dir,
                             const float* __restrict__ rbf, const int* __restrict__ offsets,
                             int* __restrict__ cursor, uint* __restrict__ edata) {
  int e = blockIdx.x * blockDim.x + threadIdx.x;
  if (e >= NE) return;
  int i = idx_i[e];
  int pos = atomicAdd(&cursor[i], 1);
  uint* d = edata + (size_t)(offsets[i] + pos) * 16;
  d[0] = (uint)idx_j[e];
  d[1] = __float_as_uint(cut[e]);
  d[2] = __float_as_uint(dir[e * 3 + 0]);
  d[3] = __float_as_uint(dir[e * 3 + 1]);
  d[4] = __float_as_uint(dir[e * 3 + 2]);
  d[5] = 0u;
  const float* rb = rbf + (size_t)e * NRBF;
#pragma unroll
  for (int r = 0; r < 10; r++) {
    uint lo = (uint)f2bf(rb[2 * r]);
    uint hi = (uint)f2bf(rb[2 * r + 1]);
    d[6 + r] = (hi << 16) | lo;
  }
}

// ---------------- node-centric accumulation: 2 nodes x 128 features ----------------
// Wg GEMV via v_dot2_f32_bf16 on packed bf16 pairs: 30 dot2/edge-thread, no unpack.
__global__ __launch_bounds__(256, 4) void node_kernel(
    const uint* __restrict__ edata, const float* __restrict__ Wr,
    const float* __restrict__ br, const ushort* __restrict__ phi_b,
    const float* __restrict__ sf, const float* __restrict__ vf,
    const ushort* __restrict__ vfb, const int* __restrict__ offsets,
    float* __restrict__ out) {
  const int t = threadIdx.x;
  const int f = t & 127;
  const int g = t >> 7;  // node slot 0..1
#if USE_DOT2
  bf16x2 wrA[10], wrB[10], wrC[10];
#pragma unroll
  for (int r = 0; r < 10; r++) {
    uint a = ((uint)f2bf(Wr[(2 * r + 1) * PHI_DIM + f]) << 16) | f2bf(Wr[(2 * r) * PHI_DIM + f]);
    uint b = ((uint)f2bf(Wr[(2 * r + 1) * PHI_DIM + f + 128]) << 16) |
             f2bf(Wr[(2 * r) * PHI_DIM + f + 128]);
    uint c = ((uint)f2bf(Wr[(2 * r + 1) * PHI_DIM + f + 256]) << 16) |
             f2bf(Wr[(2 * r) * PHI_DIM + f + 256]);
    wrA[r] = __builtin_bit_cast(bf16x2, a);
    wrB[r] = __builtin_bit_cast(bf16x2, b);
    wrC[r] = __builtin_bit_cast(bf16x2, c);
  }
#else
  float wrA[NRBF], wrB[NRBF], wrC[NRBF];
#pragma unroll
  for (int r = 0; r < NRBF; r++) {
    wrA[r] = Wr[r * PHI_DIM + f];
    wrB[r] = Wr[r * PHI_DIM + f + 128];
    wrC[r] = Wr[r * PHI_DIM + f + 256];
  }
#endif
  const int n = blockIdx.x * 2 + g;
  const int beg = offsets[n], end = offsets[n + 1];
  const float br0 = br[f], br1 = br[f + 128], br2 = br[f + 256];
  float ss = 0.f, vx = 0.f, vy = 0.f, vz = 0.f;
  for (int p = beg; p < end; p++) {
    const int pu = __builtin_amdgcn_readfirstlane(p);
    const uint4* rec = (const uint4*)(edata + (size_t)pu * 16);
    uint4 q0 = rec[0];
    uint4 q1 = rec[1];
    uint4 q2 = rec[2];
    uint4 q3 = rec[3];
    const int j = (int)q0.x;
    const float c = __uint_as_float(q0.y);
    const float dx = __uint_as_float(q0.z);
    const float dy = __uint_as_float(q0.w);
    const float dz = __uint_as_float(q1.x);
    uint rbp[10] = {q1.z, q1.w, q2.x, q2.y, q2.z, q2.w, q3.x, q3.y, q3.z, q3.w};
    float g0 = br0, g1 = br1, g2 = br2;
#if USE_DOT2
#pragma unroll
    for (int r = 0; r < 10; r++) {
      bf16x2 rp = __builtin_bit_cast(bf16x2, rbp[r]);
      g0 = __builtin_amdgcn_fdot2_f32_bf16(rp, wrA[r], g0, false);
      g1 = __builtin_amdgcn_fdot2_f32_bf16(rp, wrB[r], g1, false);
      g2 = __builtin_amdgcn_fdot2_f32_bf16(rp, wrC[r], g2, false);
    }
#else
    float rv[NRBF];
#pragma unroll
    for (int r = 0; r < 10; r++) {
      rv[2 * r] = __uint_as_float(rbp[r] << 16);
      rv[2 * r + 1] = __uint_as_float(rbp[r] & 0xffff0000u);
    }
#pragma unroll
    for (int r = 0; r < NRBF; r++) {
      float rvv = rv[r];
      g0 += rvv * wrA[r];
      g1 += rvv * wrB[r];
      g2 += rvv * wrC[r];
    }
#endif
    g0 *= c; g1 *= c; g2 *= c;
    const ushort* pj = phi_b + (size_t)j * PHI_DIM;
    const float vv = bf2f(pj[f]) * g0;
    const float sv = bf2f(pj[f + 128]) * g1;
    const float vs = bf2f(pj[f + 256]) * g2;
    ss += sv;
    const ushort* vj = vfb + (size_t)j * PHI_DIM;
    vx += bf2f(vj[f]) * vv + vs * dx;
    vy += bf2f(vj[f + 128]) * vv + vs * dy;
    vz += bf2f(vj[f + 256]) * vv + vs * dz;
  }
  const float inv = 1.0f / (float)(end - beg);
  out[(size_t)n * FDIM + f] = sf[(size_t)n * FDIM + f] + ss * inv;
  float* ov = out + (size_t)NN * FDIM + (size_t)n * (FDIM * 3) + f * 3;
  const float* iv = vf + (size_t)n * (FDIM * 3) + f * 3;
  ov[0] = iv[0] + vx * inv;
  ov[1] = iv[1] + vy * inv;
  ov[2] = iv[2] + vz * inv;
}

extern "C" void kernel_launch(void* const* d_in, const int* in_sizes, int n_in,
                              void* d_out, int out_size, void* d_ws, size_t ws_size,
                              hipStream_t stream) {
  const int* idx_i = (const int*)d_in[0];
  const int* idx_j = (const int*)d_in[1];
  const float* rel_dir = (const float*)d_in[2];
  const float* cut = (const float*)d_in[3];
  const float* rbf = (const float*)d_in[4];
  const float* sf = (const float*)d_in[5];
  const float* vf = (const float*)d_in[6];
  const float* W1 = (const float*)d_in[7];
  const float* b1 = (const float*)d_in[8];
  const float* W2 = (const float*)d_in[9];
  const float* b2 = (const float*)d_in[10];
  const float* Wr = (const float*)d_in[11];
  const float* br = (const float*)d_in[12];
  float* out = (float*)d_out;

  // workspace layout (bytes):
  //   counts   : [0, 40960)          10240 ints (zero-padded)
  //   cursor   : [40960, 81920)      10240 ints (zero-padded)
  //   offsets  : [81920, 122944)     10241 ints (padded)
  //   blocksums: [122944, 123200)    40 ints (padded to 64)
  //   edata    : [123200, 20603200)  320000 * 64 B
  //   phi_b    : [20603200, 28283200)
  //   vfb      : [28283200, 35963200)
  char* w = (char*)d_ws;
  int* counts = (int*)w;
  int* cursor = (int*)(w + 40960);
  int* offsets = (int*)(w + 81920);
  int* blocksums = (int*)(w + 122944);
  uint* edata = (uint*)(w + 123200);
  ushort* phi_b = (ushort*)(w + 20603200);
  ushort* vfb = (ushort*)(w + 28283200);

  hipMemsetAsync(w, 0, 81920, stream);  // zero counts + cursor
  hipLaunchKernelGGL(phi_kernel, dim3(NN / 8), dim3(128), 0, stream, sf, W1, b1, W2, b2, phi_b);
  hipLaunchKernelGGL(vfb_kernel, dim3(NN), dim3(128), 0, stream, vf, vfb);
  hipLaunchKernelGGL(count_kernel, dim3((NE + 255) / 256), dim3(256), 0, stream, idx_i, counts);
  hipLaunchKernelGGL(scan1_kernel, dim3(SCAN_BLOCKS), dim3(256), 0, stream, counts, offsets,
                     blocksums);
  hipLaunchKernelGGL(scan2_kernel, dim3(1), dim3(64), 0, stream, blocksums, offsets);
  hipLaunchKernelGGL(scan3_kernel, dim3(SCAN_BLOCKS), dim3(256), 0, stream, offsets, blocksums);
  hipLaunchKernelGGL(stage_kernel, dim3((NE + 255) / 256), dim3(256), 0, stream, idx_i, idx_j,
                     cut, rel_dir, rbf, offsets, cursor, edata);
  hipLaunchKernelGGL(node_kernel, dim3(NN / 2), dim3(256), 0, stream, edata, Wr, br, phi_b, sf,
                     vf, vfb, offsets, out);
}

// Round 9
// 187.861 us; speedup vs baseline: 2.6592x; 1.0908x over previous
//
#include <hip/hip_runtime.h>
#include <hip/hip_bf16.h>

#define NN 10000
#define NE 320000
#define FDIM 128
#define NRBF 20
#define PHI_DIM 384

typedef unsigned int uint;
typedef unsigned short ushort;

#if __has_builtin(__builtin_amdgcn_fdot2_f32_bf16)
#define USE_DOT2 1
typedef __bf16 bf16x2 __attribute__((ext_vector_type(2)));
#else
#define USE_DOT2 0
#endif

__device__ __forceinline__ ushort f2bf(float x) {
  __hip_bfloat16 b = __float2bfloat16(x);
  return *(ushort*)&b;
}
__device__ __forceinline__ float bf2f(ushort u) {
  return __uint_as_float(((uint)u) << 16);
}

// Packed per-node rows (768 B): uint[128] = (plane1_bf16<<16 | plane0_bf16), then
// ushort[128] = plane2_bf16.  phi planes: 0=vv, 1=ss, 2=vs.  vf planes: 0=x,1=y,2=z.

// ---------------- node MLP (+ fused vf conversion): outputs packed rows ----------------
__global__ void phi_kernel(const float* __restrict__ S, const float* __restrict__ W1,
                           const float* __restrict__ b1, const float* __restrict__ W2,
                           const float* __restrict__ b2, const float* __restrict__ vf,
                           char* __restrict__ phi_p, char* __restrict__ vf_p) {
  __shared__ float s_s[8][FDIM];
  __shared__ float h_s[8][FDIM];
  const int t = threadIdx.x;
  const int n0 = blockIdx.x * 8;
  // fused: vf -> packed bf16 rows for this block's 8 nodes
#pragma unroll
  for (int n = 0; n < 8; n++) {
    const int node = n0 + n;
    const float* src = vf + (size_t)node * (FDIM * 3) + t * 3;
    float x = src[0], y = src[1], z = src[2];
    char* vb = vf_p + (size_t)node * 768;
    ((uint*)vb)[t] = ((uint)f2bf(y) << 16) | f2bf(x);
    ((ushort*)(vb + 512))[t] = f2bf(z);
  }
#pragma unroll
  for (int n = 0; n < 8; n++) s_s[n][t] = S[(n0 + n) * FDIM + t];
  __syncthreads();
  float acc[8];
#pragma unroll
  for (int n = 0; n < 8; n++) acc[n] = 0.f;
  for (int k = 0; k < FDIM; k++) {
    float w = W1[k * FDIM + t];
#pragma unroll
    for (int n = 0; n < 8; n++) acc[n] += s_s[n][k] * w;
  }
  float bb = b1[t];
#pragma unroll
  for (int n = 0; n < 8; n++) {
    float x = acc[n] + bb;
    h_s[n][t] = x / (1.0f + expf(-x));
  }
  __syncthreads();
  float a0[8], a1[8], a2[8];
#pragma unroll
  for (int n = 0; n < 8; n++) { a0[n] = 0.f; a1[n] = 0.f; a2[n] = 0.f; }
  for (int k = 0; k < FDIM; k++) {
    float w0 = W2[k * PHI_DIM + t];
    float w1 = W2[k * PHI_DIM + t + 128];
    float w2 = W2[k * PHI_DIM + t + 256];
#pragma unroll
    for (int n = 0; n < 8; n++) {
      float hv = h_s[n][k];
      a0[n] += hv * w0;
      a1[n] += hv * w1;
      a2[n] += hv * w2;
    }
  }
  float c0 = b2[t], c1 = b2[t + 128], c2 = b2[t + 256];
#pragma unroll
  for (int n = 0; n < 8; n++) {
    char* pb = phi_p + (size_t)(n0 + n) * 768;
    ((uint*)pb)[t] = ((uint)f2bf(a1[n] + c1) << 16) | f2bf(a0[n] + c0);
    ((ushort*)(pb + 512))[t] = f2bf(a2[n] + c2);
  }
}

// ---------------- CSR build over i ----------------
__global__ void count_kernel(const int* __restrict__ idx_i, int* __restrict__ counts) {
  int e = blockIdx.x * blockDim.x + threadIdx.x;
  if (e < NE) atomicAdd(&counts[idx_i[e]], 1);
}

// single-block scan of 10000 counts (region zero-padded to 10240)
__global__ void scan_kernel(const int* __restrict__ counts, int* __restrict__ offsets) {
  __shared__ int s[1024];
  const int t = threadIdx.x;
  const int CH = 10;
  const int base = t * CH;
  int sum = 0;
#pragma unroll
  for (int i = 0; i < CH; i++) sum += counts[base + i];
  s[t] = sum;
  __syncthreads();
  for (int off = 1; off < 1024; off <<= 1) {
    int v = (t >= off) ? s[t - off] : 0;
    __syncthreads();
    s[t] += v;
    __syncthreads();
  }
  int run = s[t] - sum;  // exclusive prefix of this chunk
  for (int i = 0; i < CH; i++) {
    int idx = base + i;
    if (idx < NN) {
      offsets[idx] = run;
      run += counts[idx];
    }
  }
  if (t == 1023) offsets[NN] = s[1023];
}

// stage CSR-ordered 64-B edge records: {j, cut, dx, dy, dz, pad, rbf[20] bf16}
__global__ void stage_kernel(const int* __restrict__ idx_i, const int* __restrict__ idx_j,
                             const float* __restrict__ cut, const float* __restrict__ dir,
                             const float* __restrict__ rbf, const int* __restrict__ offsets,
                             int* __restrict__ cursor, uint* __restrict__ edata) {
  int e = blockIdx.x * blockDim.x + threadIdx.x;
  if (e >= NE) return;
  int i = idx_i[e];
  int pos = atomicAdd(&cursor[i], 1);
  uint* d = edata + (size_t)(offsets[i] + pos) * 16;
  d[0] = (uint)idx_j[e];
  d[1] = __float_as_uint(cut[e]);
  d[2] = __float_as_uint(dir[e * 3 + 0]);
  d[3] = __float_as_uint(dir[e * 3 + 1]);
  d[4] = __float_as_uint(dir[e * 3 + 2]);
  d[5] = 0u;
  const float* rb = rbf + (size_t)e * NRBF;
#pragma unroll
  for (int r = 0; r < 10; r++) {
    uint lo = (uint)f2bf(rb[2 * r]);
    uint hi = (uint)f2bf(rb[2 * r + 1]);
    d[6 + r] = (hi << 16) | lo;
  }
}

// ---------------- node-centric accumulation: 1 node per 128-thread block ----------------
__global__ __launch_bounds__(128, 6) void node_kernel(
    const uint* __restrict__ edata, const float* __restrict__ Wr,
    const float* __restrict__ br, const char* __restrict__ phi_p,
    const float* __restrict__ sf, const float* __restrict__ vf,
    const char* __restrict__ vf_p, const int* __restrict__ offsets,
    float* __restrict__ out) {
  const int f = threadIdx.x;  // 0..127
#if USE_DOT2
  bf16x2 wrA[10], wrB[10], wrC[10];
#pragma unroll
  for (int r = 0; r < 10; r++) {
    uint a = ((uint)f2bf(Wr[(2 * r + 1) * PHI_DIM + f]) << 16) | f2bf(Wr[(2 * r) * PHI_DIM + f]);
    uint b = ((uint)f2bf(Wr[(2 * r + 1) * PHI_DIM + f + 128]) << 16) |
             f2bf(Wr[(2 * r) * PHI_DIM + f + 128]);
    uint c = ((uint)f2bf(Wr[(2 * r + 1) * PHI_DIM + f + 256]) << 16) |
             f2bf(Wr[(2 * r) * PHI_DIM + f + 256]);
    wrA[r] = __builtin_bit_cast(bf16x2, a);
    wrB[r] = __builtin_bit_cast(bf16x2, b);
    wrC[r] = __builtin_bit_cast(bf16x2, c);
  }
#else
  float wrA[NRBF], wrB[NRBF], wrC[NRBF];
#pragma unroll
  for (int r = 0; r < NRBF; r++) {
    wrA[r] = Wr[r * PHI_DIM + f];
    wrB[r] = Wr[r * PHI_DIM + f + 128];
    wrC[r] = Wr[r * PHI_DIM + f + 256];
  }
#endif
  const int n = blockIdx.x;
  const int beg = offsets[n], end = offsets[n + 1];
  const float br0 = br[f], br1 = br[f + 128], br2 = br[f + 256];
  float ss = 0.f, ax = 0.f, ay = 0.f, az = 0.f;
  for (int p = beg; p < end; p++) {
    const uint4* rec = (const uint4*)(edata + (size_t)p * 16);
    uint4 q0 = rec[0];
    uint4 q1 = rec[1];
    uint4 q2 = rec[2];
    uint4 q3 = rec[3];
    const int j = (int)q0.x;
    const float c = __uint_as_float(q0.y);
    const float dx = __uint_as_float(q0.z);
    const float dy = __uint_as_float(q0.w);
    const float dz = __uint_as_float(q1.x);
    uint rbp[10] = {q1.z, q1.w, q2.x, q2.y, q2.z, q2.w, q3.x, q3.y, q3.z, q3.w};
    float g0 = br0, g1 = br1, g2 = br2;
#if USE_DOT2
#pragma unroll
    for (int r = 0; r < 10; r++) {
      bf16x2 rp = __builtin_bit_cast(bf16x2, rbp[r]);
      g0 = __builtin_amdgcn_fdot2_f32_bf16(rp, wrA[r], g0, false);
      g1 = __builtin_amdgcn_fdot2_f32_bf16(rp, wrB[r], g1, false);
      g2 = __builtin_amdgcn_fdot2_f32_bf16(rp, wrC[r], g2, false);
    }
#else
    float rv[NRBF];
#pragma unroll
    for (int r = 0; r < 10; r++) {
      rv[2 * r] = __uint_as_float(rbp[r] << 16);
      rv[2 * r + 1] = __uint_as_float(rbp[r] & 0xffff0000u);
    }
#pragma unroll
    for (int r = 0; r < NRBF; r++) {
      float rvv = rv[r];
      g0 += rvv * wrA[r];
      g1 += rvv * wrB[r];
      g2 += rvv * wrC[r];
    }
#endif
    g0 *= c; g1 *= c; g2 *= c;
    // phi gather: 1 dword + 1 ushort
    const char* pb = phi_p + (size_t)j * 768;
    const uint pq = *(const uint*)(pb + f * 4);
    const uint pz = *(const ushort*)(pb + 512 + f * 2);
    const float vv = __uint_as_float(pq << 16) * g0;          // plane0 * g0
    const float sv = __uint_as_float(pq & 0xffff0000u) * g1;  // plane1 * g1
    const float vs = __uint_as_float(pz << 16) * g2;          // plane2 * g2
    ss += sv;
    // vf gather: 1 dword + 1 ushort
    const char* vb = vf_p + (size_t)j * 768;
    const uint vq = *(const uint*)(vb + f * 4);
    const uint vzu = *(const ushort*)(vb + 512 + f * 2);
    ax += __uint_as_float(vq << 16) * vv + vs * dx;
    ay += __uint_as_float(vq & 0xffff0000u) * vv + vs * dy;
    az += __uint_as_float(vzu << 16) * vv + vs * dz;
  }
  const float inv = 1.0f / (float)(end - beg);
  out[(size_t)n * FDIM + f] = sf[(size_t)n * FDIM + f] + ss * inv;
  float* ov = out + (size_t)NN * FDIM + (size_t)n * (FDIM * 3) + f * 3;
  const float* iv = vf + (size_t)n * (FDIM * 3) + f * 3;
  ov[0] = iv[0] + ax * inv;
  ov[1] = iv[1] + ay * inv;
  ov[2] = iv[2] + az * inv;
}

extern "C" void kernel_launch(void* const* d_in, const int* in_sizes, int n_in,
                              void* d_out, int out_size, void* d_ws, size_t ws_size,
                              hipStream_t stream) {
  const int* idx_i = (const int*)d_in[0];
  const int* idx_j = (const int*)d_in[1];
  const float* rel_dir = (const float*)d_in[2];
  const float* cut = (const float*)d_in[3];
  const float* rbf = (const float*)d_in[4];
  const float* sf = (const float*)d_in[5];
  const float* vf = (const float*)d_in[6];
  const float* W1 = (const float*)d_in[7];
  const float* b1 = (const float*)d_in[8];
  const float* W2 = (const float*)d_in[9];
  const float* b2 = (const float*)d_in[10];
  const float* Wr = (const float*)d_in[11];
  const float* br = (const float*)d_in[12];
  float* out = (float*)d_out;

  // workspace layout (bytes):
  //   counts : [0, 40960)          10240 ints (zero-padded)
  //   cursor : [40960, 81920)      10240 ints (zero-padded)
  //   offsets: [81920, 122944)     10001 ints (padded)
  //   edata  : [123200, 20603200)  320000 * 64 B
  //   phi_p  : [20603200, 28283200)  10000 * 768 B packed
  //   vf_p   : [28283200, 35963200)  10000 * 768 B packed
  char* w = (char*)d_ws;
  int* counts = (int*)w;
  int* cursor = (int*)(w + 40960);
  int* offsets = (int*)(w + 81920);
  uint* edata = (uint*)(w + 123200);
  char* phi_p = w + 20603200;
  char* vf_p = w + 28283200;

  hipMemsetAsync(w, 0, 81920, stream);  // zero counts + cursor
  hipLaunchKernelGGL(phi_kernel, dim3(NN / 8), dim3(128), 0, stream, sf, W1, b1, W2, b2, vf,
                     phi_p, vf_p);
  hipLaunchKernelGGL(count_kernel, dim3((NE + 255) / 256), dim3(256), 0, stream, idx_i, counts);
  hipLaunchKernelGGL(scan_kernel, dim3(1), dim3(1024), 0, stream, counts, offsets);
  hipLaunchKernelGGL(stage_kernel, dim3((NE + 255) / 256), dim3(256), 0, stream, idx_i, idx_j,
                     cut, rel_dir, rbf, offsets, cursor, edata);
  hipLaunchKernelGGL(node_kernel, dim3(NN), dim3(128), 0, stream, edata, Wr, br, phi_p, sf, vf,
                     vf_p, offsets, out);
}

// Round 10
// 180.357 us; speedup vs baseline: 2.7698x; 1.0416x over previous
//
#include <hip/hip_runtime.h>
#include <hip/hip_bf16.h>

#define NN 10000
#define NE 320000
#define FDIM 128
#define NRBF 20
#define PHI_DIM 384

typedef unsigned int uint;
typedef unsigned short ushort;

#if __has_builtin(__builtin_amdgcn_fdot2_f32_bf16)
#define USE_DOT2 1
typedef __bf16 bf16x2 __attribute__((ext_vector_type(2)));
#else
#define USE_DOT2 0
#endif

__device__ __forceinline__ ushort f2bf(float x) {
  __hip_bfloat16 b = __float2bfloat16(x);
  return *(ushort*)&b;
}

// Interleaved per-node table row (1536 B):
//   [0,512)    uint  : phi1_bf16<<16 | phi0_bf16   (phi0=vv-gate, phi1=ss-gate)
//   [512,768)  ushort: phi2_bf16                   (vs-gate)
//   [768,1280) uint  : vfy_bf16<<16 | vfx_bf16
//   [1280,1536)ushort: vfz_bf16

// ---------------- node MLP + fused edge-count + fused vf pack ----------------
__global__ void phi_kernel(const float* __restrict__ S, const float* __restrict__ W1,
                           const float* __restrict__ b1, const float* __restrict__ W2,
                           const float* __restrict__ b2, const float* __restrict__ vf,
                           const int* __restrict__ idx_i, int* __restrict__ counts,
                           char* __restrict__ tab) {
  __shared__ float s_s[8][FDIM];
  __shared__ float h_s[8][FDIM];
  const int t = threadIdx.x;
  const int n0 = blockIdx.x * 8;
  // fused: edge counting (exactly 2 edges per thread, 1250*128*2 == NE)
  {
    const int e0 = (blockIdx.x * 128 + t) * 2;
    atomicAdd(&counts[idx_i[e0]], 1);
    atomicAdd(&counts[idx_i[e0 + 1]], 1);
  }
  // fused: vf -> packed bf16 rows
#pragma unroll
  for (int n = 0; n < 8; n++) {
    const int node = n0 + n;
    const float* src = vf + (size_t)node * (FDIM * 3) + t * 3;
    char* vb = tab + (size_t)node * 1536 + 768;
    ((uint*)vb)[t] = ((uint)f2bf(src[1]) << 16) | f2bf(src[0]);
    ((ushort*)(vb + 512))[t] = f2bf(src[2]);
  }
#pragma unroll
  for (int n = 0; n < 8; n++) s_s[n][t] = S[(n0 + n) * FDIM + t];
  __syncthreads();
  float acc[8];
#pragma unroll
  for (int n = 0; n < 8; n++) acc[n] = 0.f;
  for (int k = 0; k < FDIM; k++) {
    float w = W1[k * FDIM + t];
#pragma unroll
    for (int n = 0; n < 8; n++) acc[n] += s_s[n][k] * w;
  }
  float bb = b1[t];
#pragma unroll
  for (int n = 0; n < 8; n++) {
    float x = acc[n] + bb;
    h_s[n][t] = x / (1.0f + expf(-x));
  }
  __syncthreads();
  float a0[8], a1[8], a2[8];
#pragma unroll
  for (int n = 0; n < 8; n++) { a0[n] = 0.f; a1[n] = 0.f; a2[n] = 0.f; }
  for (int k = 0; k < FDIM; k++) {
    float w0 = W2[k * PHI_DIM + t];
    float w1 = W2[k * PHI_DIM + t + 128];
    float w2 = W2[k * PHI_DIM + t + 256];
#pragma unroll
    for (int n = 0; n < 8; n++) {
      float hv = h_s[n][k];
      a0[n] += hv * w0;
      a1[n] += hv * w1;
      a2[n] += hv * w2;
    }
  }
  float c0 = b2[t], c1 = b2[t + 128], c2 = b2[t + 256];
#pragma unroll
  for (int n = 0; n < 8; n++) {
    char* pb = tab + (size_t)(n0 + n) * 1536;
    ((uint*)pb)[t] = ((uint)f2bf(a1[n] + c1) << 16) | f2bf(a0[n] + c0);
    ((ushort*)(pb + 512))[t] = f2bf(a2[n] + c2);
  }
}

// single-block scan of 10000 counts (region zero-padded to 10240)
__global__ void scan_kernel(const int* __restrict__ counts, int* __restrict__ offsets) {
  __shared__ int s[1024];
  const int t = threadIdx.x;
  const int CH = 10;
  const int base = t * CH;
  int sum = 0;
#pragma unroll
  for (int i = 0; i < CH; i++) sum += counts[base + i];
  s[t] = sum;
  __syncthreads();
  for (int off = 1; off < 1024; off <<= 1) {
    int v = (t >= off) ? s[t - off] : 0;
    __syncthreads();
    s[t] += v;
    __syncthreads();
  }
  int run = s[t] - sum;
  for (int i = 0; i < CH; i++) {
    int idx = base + i;
    if (idx < NN) {
      offsets[idx] = run;
      run += counts[idx];
    }
  }
  if (t == 1023) offsets[NN] = s[1023];
}

// stage CSR-ordered 64-B edge records: {j, cut, dx, dy, dz, pad, (rbf*cut)[20] bf16}
__global__ void stage_kernel(const int* __restrict__ idx_i, const int* __restrict__ idx_j,
                             const float* __restrict__ cut, const float* __restrict__ dir,
                             const float* __restrict__ rbf, const int* __restrict__ offsets,
                             int* __restrict__ cursor, uint* __restrict__ edata) {
  int e = blockIdx.x * blockDim.x + threadIdx.x;
  if (e >= NE) return;
  int i = idx_i[e];
  int pos = atomicAdd(&cursor[i], 1);
  uint* d = edata + (size_t)(offsets[i] + pos) * 16;
  const float c = cut[e];
  d[0] = (uint)idx_j[e];
  d[1] = __float_as_uint(c);
  d[2] = __float_as_uint(dir[e * 3 + 0]);
  d[3] = __float_as_uint(dir[e * 3 + 1]);
  d[4] = __float_as_uint(dir[e * 3 + 2]);
  d[5] = 0u;
  const float* rb = rbf + (size_t)e * NRBF;
#pragma unroll
  for (int r = 0; r < 10; r++) {
    uint lo = (uint)f2bf(rb[2 * r] * c);
    uint hi = (uint)f2bf(rb[2 * r + 1] * c);
    d[6 + r] = (hi << 16) | lo;
  }
}

// ---------------- node-centric accumulation: 1 node per 128-thread block ----------------
__global__ __launch_bounds__(128, 8) void node_kernel(
    const uint* __restrict__ edata, const float* __restrict__ Wr,
    const float* __restrict__ br, const char* __restrict__ tab,
    const float* __restrict__ sf, const float* __restrict__ vf,
    const int* __restrict__ offsets, float* __restrict__ out) {
  const int f = threadIdx.x;  // 0..127
#if USE_DOT2
  bf16x2 wrA[10], wrB[10], wrC[10];
#pragma unroll
  for (int r = 0; r < 10; r++) {
    uint a = ((uint)f2bf(Wr[(2 * r + 1) * PHI_DIM + f]) << 16) | f2bf(Wr[(2 * r) * PHI_DIM + f]);
    uint b = ((uint)f2bf(Wr[(2 * r + 1) * PHI_DIM + f + 128]) << 16) |
             f2bf(Wr[(2 * r) * PHI_DIM + f + 128]);
    uint c = ((uint)f2bf(Wr[(2 * r + 1) * PHI_DIM + f + 256]) << 16) |
             f2bf(Wr[(2 * r) * PHI_DIM + f + 256]);
    wrA[r] = __builtin_bit_cast(bf16x2, a);
    wrB[r] = __builtin_bit_cast(bf16x2, b);
    wrC[r] = __builtin_bit_cast(bf16x2, c);
  }
#else
  float wrA[NRBF], wrB[NRBF], wrC[NRBF];
#pragma unroll
  for (int r = 0; r < NRBF; r++) {
    wrA[r] = Wr[r * PHI_DIM + f];
    wrB[r] = Wr[r * PHI_DIM + f + 128];
    wrC[r] = Wr[r * PHI_DIM + f + 256];
  }
#endif
  const int n = blockIdx.x;
  const int beg = offsets[n], end = offsets[n + 1];
  const float br0 = br[f], br1 = br[f + 128], br2 = br[f + 256];
  float ss = 0.f, ax = 0.f, ay = 0.f, az = 0.f;
  for (int p = beg; p < end; p++) {
    const uint4* rec = (const uint4*)(edata + (size_t)p * 16);
    uint4 q0 = rec[0];
    uint4 q1 = rec[1];
    uint4 q2 = rec[2];
    uint4 q3 = rec[3];
    const int j = (int)q0.x;
    const float c = __uint_as_float(q0.y);
    const float dx = __uint_as_float(q0.z);
    const float dy = __uint_as_float(q0.w);
    const float dz = __uint_as_float(q1.x);
    uint rbp[10] = {q1.z, q1.w, q2.x, q2.y, q2.z, q2.w, q3.x, q3.y, q3.z, q3.w};
    float g0 = 0.f, g1 = 0.f, g2 = 0.f;  // rbf pre-scaled by cut; bias added below
#if USE_DOT2
#pragma unroll
    for (int r = 0; r < 10; r++) {
      bf16x2 rp = __builtin_bit_cast(bf16x2, rbp[r]);
      g0 = __builtin_amdgcn_fdot2_f32_bf16(rp, wrA[r], g0, false);
      g1 = __builtin_amdgcn_fdot2_f32_bf16(rp, wrB[r], g1, false);
      g2 = __builtin_amdgcn_fdot2_f32_bf16(rp, wrC[r], g2, false);
    }
#else
    float rv[NRBF];
#pragma unroll
    for (int r = 0; r < 10; r++) {
      rv[2 * r] = __uint_as_float(rbp[r] << 16);
      rv[2 * r + 1] = __uint_as_float(rbp[r] & 0xffff0000u);
    }
#pragma unroll
    for (int r = 0; r < NRBF; r++) {
      float rvv = rv[r];
      g0 += rvv * wrA[r];
      g1 += rvv * wrB[r];
      g2 += rvv * wrC[r];
    }
#endif
    g0 += br0 * c;
    g1 += br1 * c;
    g2 += br2 * c;
    // single gather base for interleaved phi/vf row
    const char* base = tab + (size_t)j * 1536;
    const uint pq = *(const uint*)(base + f * 4);
    const uint pz = *(const ushort*)(base + 512 + f * 2);
    const uint vq = *(const uint*)(base + 768 + f * 4);
    const uint vzu = *(const ushort*)(base + 1280 + f * 2);
    const float vv = __uint_as_float(pq << 16) * g0;
    const float sv = __uint_as_float(pq & 0xffff0000u) * g1;
    const float vs = __uint_as_float(pz << 16) * g2;
    ss += sv;
    ax += __uint_as_float(vq << 16) * vv + vs * dx;
    ay += __uint_as_float(vq & 0xffff0000u) * vv + vs * dy;
    az += __uint_as_float(vzu << 16) * vv + vs * dz;
  }
  const float inv = 1.0f / (float)(end - beg);
  out[(size_t)n * FDIM + f] = sf[(size_t)n * FDIM + f] + ss * inv;
  float* ov = out + (size_t)NN * FDIM + (size_t)n * (FDIM * 3) + f * 3;
  const float* iv = vf + (size_t)n * (FDIM * 3) + f * 3;
  ov[0] = iv[0] + ax * inv;
  ov[1] = iv[1] + ay * inv;
  ov[2] = iv[2] + az * inv;
}

extern "C" void kernel_launch(void* const* d_in, const int* in_sizes, int n_in,
                              void* d_out, int out_size, void* d_ws, size_t ws_size,
                              hipStream_t stream) {
  const int* idx_i = (const int*)d_in[0];
  const int* idx_j = (const int*)d_in[1];
  const float* rel_dir = (const float*)d_in[2];
  const float* cut = (const float*)d_in[3];
  const float* rbf = (const float*)d_in[4];
  const float* sf = (const float*)d_in[5];
  const float* vf = (const float*)d_in[6];
  const float* W1 = (const float*)d_in[7];
  const float* b1 = (const float*)d_in[8];
  const float* W2 = (const float*)d_in[9];
  const float* b2 = (const float*)d_in[10];
  const float* Wr = (const float*)d_in[11];
  const float* br = (const float*)d_in[12];
  float* out = (float*)d_out;

  // workspace layout (bytes):
  //   counts : [0, 40960)          10240 ints (zero-padded)
  //   cursor : [40960, 81920)      10240 ints (zero-padded)
  //   offsets: [81920, 122944)     10001 ints (padded)
  //   edata  : [123200, 20603200)  320000 * 64 B
  //   tab    : [20603200, 35963200) 10000 * 1536 B interleaved phi/vf
  char* w = (char*)d_ws;
  int* counts = (int*)w;
  int* cursor = (int*)(w + 40960);
  int* offsets = (int*)(w + 81920);
  uint* edata = (uint*)(w + 123200);
  char* tab = w + 20603200;

  hipMemsetAsync(w, 0, 81920, stream);  // zero counts + cursor
  hipLaunchKernelGGL(phi_kernel, dim3(NN / 8), dim3(128), 0, stream, sf, W1, b1, W2, b2, vf,
                     idx_i, counts, tab);
  hipLaunchKernelGGL(scan_kernel, dim3(1), dim3(1024), 0, stream, counts, offsets);
  hipLaunchKernelGGL(stage_kernel, dim3((NE + 255) / 256), dim3(256), 0, stream, idx_i, idx_j,
                     cut, rel_dir, rbf, offsets, cursor, edata);
  hipLaunchKernelGGL(node_kernel, dim3(NN), dim3(128), 0, stream, edata, Wr, br, tab, sf, vf,
                     offsets, out);
}

// Round 11
// 165.648 us; speedup vs baseline: 3.0158x; 1.0888x over previous
//
#include <hip/hip_runtime.h>
#include <hip/hip_bf16.h>

#define NN 10000
#define NE 320000
#define FDIM 128
#define NRBF 20
#define PHI_DIM 384
#define NKEY NN
#define SCAN_BLOCKS 40  // 40*256 = 10240 >= NKEY+1

typedef unsigned int uint;
typedef unsigned short ushort;

#if __has_builtin(__builtin_amdgcn_fdot2_f32_bf16)
#define USE_DOT2 1
typedef __bf16 bf16x2 __attribute__((ext_vector_type(2)));
#else
#define USE_DOT2 0
#endif

__device__ __forceinline__ ushort f2bf(float x) {
  __hip_bfloat16 b = __float2bfloat16(x);
  return *(ushort*)&b;
}

// Interleaved per-node table row (1536 B), 3 dword gathers per edge:
//   [0,512)     uint: phi1_bf16<<16 | phi0_bf16   (vv-gate, ss-gate)
//   [512,1024)  uint: vfz_bf16 <<16 | phi2_bf16   (z-plane pair)
//   [1024,1536) uint: vfy_bf16 <<16 | vfx_bf16

// ---------------- node MLP + fused edge-count + fused vf pack ----------------
__global__ void phi_kernel(const float* __restrict__ S, const float* __restrict__ W1,
                           const float* __restrict__ b1, const float* __restrict__ W2,
                           const float* __restrict__ b2, const float* __restrict__ vf,
                           const int* __restrict__ idx_i, int* __restrict__ counts,
                           char* __restrict__ tab) {
  __shared__ float s_s[8][FDIM];
  __shared__ float h_s[8][FDIM];
  const int t = threadIdx.x;
  const int n0 = blockIdx.x * 8;
  // fused: edge counting (exactly 2 edges per thread, 1250*128*2 == NE)
  {
    const int e0 = (blockIdx.x * 128 + t) * 2;
    atomicAdd(&counts[idx_i[e0]], 1);
    atomicAdd(&counts[idx_i[e0 + 1]], 1);
  }
  // fused: vf -> packed rows (x,y now; z held for the combined z-word)
  ushort vz[8];
#pragma unroll
  for (int n = 0; n < 8; n++) {
    const int node = n0 + n;
    const float* src = vf + (size_t)node * (FDIM * 3) + t * 3;
    char* pb = tab + (size_t)node * 1536;
    ((uint*)(pb + 1024))[t] = ((uint)f2bf(src[1]) << 16) | f2bf(src[0]);
    vz[n] = f2bf(src[2]);
  }
#pragma unroll
  for (int n = 0; n < 8; n++) s_s[n][t] = S[(n0 + n) * FDIM + t];
  __syncthreads();
  float acc[8];
#pragma unroll
  for (int n = 0; n < 8; n++) acc[n] = 0.f;
  for (int k = 0; k < FDIM; k++) {
    float w = W1[k * FDIM + t];
#pragma unroll
    for (int n = 0; n < 8; n++) acc[n] += s_s[n][k] * w;
  }
  float bb = b1[t];
#pragma unroll
  for (int n = 0; n < 8; n++) {
    float x = acc[n] + bb;
    h_s[n][t] = x / (1.0f + expf(-x));
  }
  __syncthreads();
  float a0[8], a1[8], a2[8];
#pragma unroll
  for (int n = 0; n < 8; n++) { a0[n] = 0.f; a1[n] = 0.f; a2[n] = 0.f; }
  for (int k = 0; k < FDIM; k++) {
    float w0 = W2[k * PHI_DIM + t];
    float w1 = W2[k * PHI_DIM + t + 128];
    float w2 = W2[k * PHI_DIM + t + 256];
#pragma unroll
    for (int n = 0; n < 8; n++) {
      float hv = h_s[n][k];
      a0[n] += hv * w0;
      a1[n] += hv * w1;
      a2[n] += hv * w2;
    }
  }
  float c0 = b2[t], c1 = b2[t + 128], c2 = b2[t + 256];
#pragma unroll
  for (int n = 0; n < 8; n++) {
    char* pb = tab + (size_t)(n0 + n) * 1536;
    ((uint*)pb)[t] = ((uint)f2bf(a1[n] + c1) << 16) | f2bf(a0[n] + c0);
    ((uint*)(pb + 512))[t] = ((uint)vz[n] << 16) | f2bf(a2[n] + c2);
  }
}

// ---------------- hierarchical scan: block scan -> sum scan -> add base ----------------
__global__ void scan1_kernel(const int* __restrict__ counts, int* __restrict__ offsets,
                             int* __restrict__ blocksums) {
  __shared__ int s[256];
  const int t = threadIdx.x;
  const int idx = blockIdx.x * 256 + t;
  const int c = counts[idx];  // region zero-padded to 10240
  s[t] = c;
  __syncthreads();
  for (int off = 1; off < 256; off <<= 1) {
    int v = (t >= off) ? s[t - off] : 0;
    __syncthreads();
    s[t] += v;
    __syncthreads();
  }
  if (idx < NKEY) offsets[idx] = s[t] - c;
  if (t == 255) blocksums[blockIdx.x] = s[255];
}

__global__ void scan2_kernel(int* __restrict__ blocksums, int* __restrict__ offsets) {
  __shared__ int s[64];
  const int t = threadIdx.x;  // 64 threads
  int v0 = (t < SCAN_BLOCKS) ? blocksums[t] : 0;
  s[t] = v0;
  __syncthreads();
  for (int off = 1; off < 64; off <<= 1) {
    int v = (t >= off) ? s[t - off] : 0;
    __syncthreads();
    s[t] += v;
    __syncthreads();
  }
  if (t < SCAN_BLOCKS) blocksums[t] = s[t] - v0;   // exclusive base per block
  if (t == SCAN_BLOCKS - 1) offsets[NKEY] = s[t];  // total = NE
}

__global__ void scan3_kernel(int* __restrict__ offsets, const int* __restrict__ blocksums) {
  const int idx = blockIdx.x * 256 + threadIdx.x;
  if (idx < NKEY) offsets[idx] += blocksums[blockIdx.x];  // must NOT touch offsets[NKEY]
}

// stage CSR-ordered: jlist (4 B) + 64-B records {j, cut, dx, dy, dz, pad, (rbf*cut)[20] bf16}
__global__ void stage_kernel(const int* __restrict__ idx_i, const int* __restrict__ idx_j,
                             const float* __restrict__ cut, const float* __restrict__ dir,
                             const float* __restrict__ rbf, const int* __restrict__ offsets,
                             int* __restrict__ cursor, uint* __restrict__ edata,
                             int* __restrict__ jlist) {
  int e = blockIdx.x * blockDim.x + threadIdx.x;
  if (e >= NE) return;
  int i = idx_i[e];
  int pos = atomicAdd(&cursor[i], 1);
  const int slot = offsets[i] + pos;
  const int j = idx_j[e];
  jlist[slot] = j;
  uint* d = edata + (size_t)slot * 16;
  const float c = cut[e];
  d[0] = (uint)j;
  d[1] = __float_as_uint(c);
  d[2] = __float_as_uint(dir[e * 3 + 0]);
  d[3] = __float_as_uint(dir[e * 3 + 1]);
  d[4] = __float_as_uint(dir[e * 3 + 2]);
  d[5] = 0u;
  const float* rb = rbf + (size_t)e * NRBF;
#pragma unroll
  for (int r = 0; r < 10; r++) {
    uint lo = (uint)f2bf(rb[2 * r] * c);
    uint hi = (uint)f2bf(rb[2 * r + 1] * c);
    d[6 + r] = (hi << 16) | lo;
  }
}

// ---------------- node-centric accumulation: 1 node / 128-thread block, 2-edge pipeline ----
__global__ __launch_bounds__(128, 5) void node_kernel(
    const uint* __restrict__ edata, const int* __restrict__ jlist,
    const float* __restrict__ Wr, const float* __restrict__ br,
    const char* __restrict__ tab, const float* __restrict__ sf,
    const float* __restrict__ vf, const int* __restrict__ offsets,
    float* __restrict__ out) {
  const int f = threadIdx.x;  // 0..127
#if USE_DOT2
  bf16x2 wrA[10], wrB[10], wrC[10];
#pragma unroll
  for (int r = 0; r < 10; r++) {
    uint a = ((uint)f2bf(Wr[(2 * r + 1) * PHI_DIM + f]) << 16) | f2bf(Wr[(2 * r) * PHI_DIM + f]);
    uint b = ((uint)f2bf(Wr[(2 * r + 1) * PHI_DIM + f + 128]) << 16) |
             f2bf(Wr[(2 * r) * PHI_DIM + f + 128]);
    uint c = ((uint)f2bf(Wr[(2 * r + 1) * PHI_DIM + f + 256]) << 16) |
             f2bf(Wr[(2 * r) * PHI_DIM + f + 256]);
    wrA[r] = __builtin_bit_cast(bf16x2, a);
    wrB[r] = __builtin_bit_cast(bf16x2, b);
    wrC[r] = __builtin_bit_cast(bf16x2, c);
  }
#else
  float wrA[NRBF], wrB[NRBF], wrC[NRBF];
#pragma unroll
  for (int r = 0; r < NRBF; r++) {
    wrA[r] = Wr[r * PHI_DIM + f];
    wrB[r] = Wr[r * PHI_DIM + f + 128];
    wrC[r] = Wr[r * PHI_DIM + f + 256];
  }
#endif
  const int n = blockIdx.x;
  const int beg = offsets[n], end = offsets[n + 1];
  const float br0 = br[f], br1 = br[f + 128], br2 = br[f + 256];
  float ss = 0.f, ax = 0.f, ay = 0.f, az = 0.f;
  const int f4 = f * 4;

  auto process = [&](const uint4* rec, uint pq, uint zq, uint vq) {
    uint4 q0 = rec[0];
    uint4 q1 = rec[1];
    uint4 q2 = rec[2];
    uint4 q3 = rec[3];
    const float c = __uint_as_float(q0.y);
    const float dx = __uint_as_float(q0.z);
    const float dy = __uint_as_float(q0.w);
    const float dz = __uint_as_float(q1.x);
    uint rbp[10] = {q1.z, q1.w, q2.x, q2.y, q2.z, q2.w, q3.x, q3.y, q3.z, q3.w};
    float g0 = 0.f, g1 = 0.f, g2 = 0.f;  // rbf pre-scaled by cut; bias added below
#if USE_DOT2
#pragma unroll
    for (int r = 0; r < 10; r++) {
      bf16x2 rp = __builtin_bit_cast(bf16x2, rbp[r]);
      g0 = __builtin_amdgcn_fdot2_f32_bf16(rp, wrA[r], g0, false);
      g1 = __builtin_amdgcn_fdot2_f32_bf16(rp, wrB[r], g1, false);
      g2 = __builtin_amdgcn_fdot2_f32_bf16(rp, wrC[r], g2, false);
    }
#else
#pragma unroll
    for (int r = 0; r < 10; r++) {
      float rlo = __uint_as_float(rbp[r] << 16);
      float rhi = __uint_as_float(rbp[r] & 0xffff0000u);
      g0 += rlo * wrA[2 * r] + rhi * wrA[2 * r + 1];
      g1 += rlo * wrB[2 * r] + rhi * wrB[2 * r + 1];
      g2 += rlo * wrC[2 * r] + rhi * wrC[2 * r + 1];
    }
#endif
    g0 += br0 * c;
    g1 += br1 * c;
    g2 += br2 * c;
    const float vv = __uint_as_float(pq << 16) * g0;          // phi0
    const float sv = __uint_as_float(pq & 0xffff0000u) * g1;  // phi1
    const float vs = __uint_as_float(zq << 16) * g2;          // phi2
    ss += sv;
    ax += __uint_as_float(vq << 16) * vv + vs * dx;           // vfx
    ay += __uint_as_float(vq & 0xffff0000u) * vv + vs * dy;   // vfy
    az += __uint_as_float(zq & 0xffff0000u) * vv + vs * dz;   // vfz
  };

  int p = beg;
  for (; p + 2 <= end; p += 2) {
    const int j0 = jlist[p];
    const int j1 = jlist[p + 1];
    const char* B0 = tab + (size_t)j0 * 1536;
    const char* B1 = tab + (size_t)j1 * 1536;
    const uint pq0 = *(const uint*)(B0 + f4);
    const uint zq0 = *(const uint*)(B0 + 512 + f4);
    const uint vq0 = *(const uint*)(B0 + 1024 + f4);
    const uint pq1 = *(const uint*)(B1 + f4);
    const uint zq1 = *(const uint*)(B1 + 512 + f4);
    const uint vq1 = *(const uint*)(B1 + 1024 + f4);
    const uint4* r0 = (const uint4*)(edata + (size_t)p * 16);
    const uint4* r1 = (const uint4*)(edata + (size_t)(p + 1) * 16);
    process(r0, pq0, zq0, vq0);
    process(r1, pq1, zq1, vq1);
  }
  if (p < end) {
    const int j0 = jlist[p];
    const char* B0 = tab + (size_t)j0 * 1536;
    const uint pq0 = *(const uint*)(B0 + f4);
    const uint zq0 = *(const uint*)(B0 + 512 + f4);
    const uint vq0 = *(const uint*)(B0 + 1024 + f4);
    process((const uint4*)(edata + (size_t)p * 16), pq0, zq0, vq0);
  }

  const float inv = 1.0f / (float)(end - beg);
  out[(size_t)n * FDIM + f] = sf[(size_t)n * FDIM + f] + ss * inv;
  float* ov = out + (size_t)NN * FDIM + (size_t)n * (FDIM * 3) + f * 3;
  const float* iv = vf + (size_t)n * (FDIM * 3) + f * 3;
  ov[0] = iv[0] + ax * inv;
  ov[1] = iv[1] + ay * inv;
  ov[2] = iv[2] + az * inv;
}

extern "C" void kernel_launch(void* const* d_in, const int* in_sizes, int n_in,
                              void* d_out, int out_size, void* d_ws, size_t ws_size,
                              hipStream_t stream) {
  const int* idx_i = (const int*)d_in[0];
  const int* idx_j = (const int*)d_in[1];
  const float* rel_dir = (const float*)d_in[2];
  const float* cut = (const float*)d_in[3];
  const float* rbf = (const float*)d_in[4];
  const float* sf = (const float*)d_in[5];
  const float* vf = (const float*)d_in[6];
  const float* W1 = (const float*)d_in[7];
  const float* b1 = (const float*)d_in[8];
  const float* W2 = (const float*)d_in[9];
  const float* b2 = (const float*)d_in[10];
  const float* Wr = (const float*)d_in[11];
  const float* br = (const float*)d_in[12];
  float* out = (float*)d_out;

  // workspace layout (bytes):
  //   counts   : [0, 40960)           10240 ints (zero-padded)
  //   cursor   : [40960, 81920)       10240 ints (zero-padded)
  //   offsets  : [81920, 122884)      10001 ints
  //   blocksums: [122944, 123104)     40 ints
  //   edata    : [123200, 20603200)   320000 * 64 B
  //   tab      : [20603200, 35963200) 10000 * 1536 B interleaved phi/vf
  //   jlist    : [35963200, 37243200) 320000 ints
  char* w = (char*)d_ws;
  int* counts = (int*)w;
  int* cursor = (int*)(w + 40960);
  int* offsets = (int*)(w + 81920);
  int* blocksums = (int*)(w + 122944);
  uint* edata = (uint*)(w + 123200);
  char* tab = w + 20603200;
  int* jlist = (int*)(w + 35963200);

  hipMemsetAsync(w, 0, 81920, stream);  // zero counts + cursor
  hipLaunchKernelGGL(phi_kernel, dim3(NN / 8), dim3(128), 0, stream, sf, W1, b1, W2, b2, vf,
                     idx_i, counts, tab);
  hipLaunchKernelGGL(scan1_kernel, dim3(SCAN_BLOCKS), dim3(256), 0, stream, counts, offsets,
                     blocksums);
  hipLaunchKernelGGL(scan2_kernel, dim3(1), dim3(64), 0, stream, blocksums, offsets);
  hipLaunchKernelGGL(scan3_kernel, dim3(SCAN_BLOCKS), dim3(256), 0, stream, offsets, blocksums);
  hipLaunchKernelGGL(stage_kernel, dim3((NE + 255) / 256), dim3(256), 0, stream, idx_i, idx_j,
                     cut, rel_dir, rbf, offsets, cursor, edata, jlist);
  hipLaunchKernelGGL(node_kernel, dim3(NN), dim3(128), 0, stream, edata, jlist, Wr, br, tab, sf,
                     vf, offsets, out);
}